// Round 12
// baseline (874.601 us; speedup 1.0000x reference)
//
#include <hip/hip_runtime.h>
#include <hip/hip_bf16.h>
#include <hip/hip_fp16.h>

#define NN 50000
#define NE 800000
#define FIN 128
#define HCC 256   // HEADS*HID
#define OC 64
#define NSL 0.2f
#define NT3 (3 * NN)
#define RB1 1564  // row-blocks of 32 covering mgemm's max row reach (782*64+32)/32

typedef __attribute__((ext_vector_type(8))) short sh8;
typedef __attribute__((ext_vector_type(16))) float f32x16;

struct __attribute__((aligned(8))) h4 { __half x, y, z, w; };
struct __attribute__((aligned(8))) s4 { short x, y, z, w; };

typedef const __attribute__((address_space(1))) unsigned int* gas_t;
typedef __attribute__((address_space(3))) unsigned int* las_t;

__device__ __forceinline__ unsigned short bf_rne(float f) {
  unsigned u = __float_as_uint(f);
  u += 0x7FFF + ((u >> 16) & 1);
  return (unsigned short)(u >> 16);
}

__device__ __forceinline__ float edge_w(float lg) {
  lg = (lg > 0.f) ? lg : NSL * lg;
  return __expf(lg);
}

// -------- weight pre-split into per-K-step contiguous chunks (unchanged) --------
// W:[3][KK][256] fp32 -> out:[3][kst][q(8)][c(128)][kj(8)] bf16
template<int KK>
__global__ __launch_bounds__(256) void k_prep(const float* __restrict__ W,
                                              short* __restrict__ out) {
  int i = blockIdx.x * 256 + threadIdx.x;
  if (i >= 3 * KK * 256) return;
  int r = i / (KK * 256);
  int rem = i - r * KK * 256;
  int k = rem >> 8;
  int n = rem & 255;
  float f = W[i];
  unsigned short hb = bf_rne(f);
  float hf = __uint_as_float(((unsigned)hb) << 16);
  unsigned short lb = bf_rne(f - hf);
  int cb = n >> 7, c = n & 127;
  int kst = k >> 4, p = (k >> 3) & 1, kj = k & 7;
  size_t base = (size_t)r * 4 * KK * 128;
  size_t oh = base + ((size_t)(kst * 8 + (cb * 2 + 0) * 2 + p) * 128 + c) * 8 + kj;
  size_t ol = base + ((size_t)(kst * 8 + (cb * 2 + 1) * 2 + p) * 128 + c) * 8 + kj;
  out[oh] = (short)hb;
  out[ol] = (short)lb;
}

// -------- x fp32 -> packed split-bf16 A-fragment layout --------
// xpk: [rb][kst(8)][lg(2)][hl(2)][l31(32)][8]  (per (rb,kst,lg): hi 256 + lo 256 shorts)
__global__ __launch_bounds__(256) void k_split(const float* __restrict__ x,
                                               short* __restrict__ xpk) {
  int i = blockIdx.x * 256 + threadIdx.x;
  if (i >= NN * 32) return;
  int n = i >> 5, q = i & 31;
  float4 v = *(const float4*)&x[(size_t)n * FIN + q * 4];
  int rb = n >> 5, l31 = n & 31;
  int kst = q >> 2, lg = (q >> 1) & 1, kj0 = (q & 1) * 4;
  size_t base = ((size_t)(rb * 8 + kst) * 2 + lg) * 512;
  s4 h, l;
  float f, hf;
  f = v.x; h.x = (short)bf_rne(f); hf = __uint_as_float(((unsigned)(unsigned short)h.x) << 16); l.x = (short)bf_rne(f - hf);
  f = v.y; h.y = (short)bf_rne(f); hf = __uint_as_float(((unsigned)(unsigned short)h.y) << 16); l.y = (short)bf_rne(f - hf);
  f = v.z; h.z = (short)bf_rne(f); hf = __uint_as_float(((unsigned)(unsigned short)h.z) << 16); l.z = (short)bf_rne(f - hf);
  f = v.w; h.w = (short)bf_rne(f); hf = __uint_as_float(((unsigned)(unsigned short)h.w) << 16); l.w = (short)bf_rne(f - hf);
  *(s4*)&xpk[base + l31 * 8 + kj0] = h;
  *(s4*)&xpk[base + 256 + l31 * 8 + kj0] = l;
}

// ---------------- CSR build ----------------
__global__ void k_hist3(const int* __restrict__ e0, const int* __restrict__ e1,
                        const int* __restrict__ e2, int* __restrict__ deg3) {
  int i = blockIdx.x * blockDim.x + threadIdx.x;
  int st = gridDim.x * blockDim.x;
  for (; i < 3 * NE; i += st) {
    int rel = i / NE;
    int j = i - rel * NE;
    const int* e = (rel == 0) ? e0 : ((rel == 1) ? e1 : e2);
    atomicAdd(&deg3[rel * NN + e[NE + j]], 1);
  }
}

__global__ __launch_bounds__(1024) void k_bsum(const int* __restrict__ deg3,
                                               int* __restrict__ bsum) {
  __shared__ int s[1024];
  int t = threadIdx.x;
  int i = blockIdx.x * 1024 + t;
  s[t] = (i < NT3) ? deg3[i] : 0;
  __syncthreads();
  for (int off = 512; off > 0; off >>= 1) {
    if (t < off) s[t] += s[t + off];
    __syncthreads();
  }
  if (t == 0) bsum[blockIdx.x] = s[0];
}

__global__ __launch_bounds__(256) void k_scan2(const int* __restrict__ bsum,
                                               int* __restrict__ boffs, int nb) {
  __shared__ int s[256];
  int t = threadIdx.x;
  int v = (t < nb) ? bsum[t] : 0;
  s[t] = v;
  __syncthreads();
  for (int off = 1; off < 256; off <<= 1) {
    int x = (t >= off) ? s[t - off] : 0;
    __syncthreads();
    s[t] += x;
    __syncthreads();
  }
  if (t < nb) boffs[t] = s[t] - v;  // exclusive
}

__global__ __launch_bounds__(1024) void k_rowptr(const int* __restrict__ deg3,
                                                 const int* __restrict__ boffs,
                                                 int* __restrict__ rpA,
                                                 int* __restrict__ cursor3) {
  __shared__ int s[1024];
  int t = threadIdx.x;
  int i = blockIdx.x * 1024 + t;
  int d = (i < NT3) ? deg3[i] : 0;
  s[t] = d;
  __syncthreads();
  for (int off = 1; off < 1024; off <<= 1) {
    int x = (t >= off) ? s[t - off] : 0;
    __syncthreads();
    s[t] += x;
    __syncthreads();
  }
  if (i < NT3) {
    int excl = boffs[blockIdx.x] + s[t] - d;
    int r = (i < NN) ? 0 : ((i < 2 * NN) ? 1 : 2);
    int n = i - r * NN;
    int val = excl - r * NE;
    rpA[r * (NN + 1) + n] = val;
    cursor3[i] = val;
  }
  if (blockIdx.x == 0 && t < 3) rpA[t * (NN + 1) + NN] = NE;
}

// one relation per launch: random-write region (3.2 MB) stays L2-resident
__global__ void k_scatter(const int* __restrict__ srcv, const int* __restrict__ dstv,
                          int* __restrict__ cursor, int* __restrict__ csr_src, int n) {
  int i = blockIdx.x * blockDim.x + threadIdx.x;
  int st = gridDim.x * blockDim.x;
  for (; i < n; i += st) {
    int pos = atomicAdd(&cursor[dstv[i]], 1);
    csr_src[pos] = srcv[i];
  }
}

// -------- split-bf16 MFMA GEMM (32x32x16), LDS-staged B, packed-coalesced A --------
template<int KK>
__global__ __launch_bounds__(256) void k_mgemm(const short* __restrict__ Apk,
                                               const short* __restrict__ BcAll,
                                               const float* __restrict__ asfAll,
                                               const float* __restrict__ adfAll,
                                               __half* __restrict__ houtAll,
                                               float* __restrict__ alsAll,
                                               float* __restrict__ aldAll, int M) {
  __shared__ short Bs[2][8192];  // 2 x 16 KB
  const int rel = blockIdx.y;
  const short* Brel = BcAll + (size_t)rel * 4 * KK * 128;
  const float* asf = asfAll + rel * HCC;
  const float* adf = adfAll + rel * HCC;
  __half* hout = houtAll + (size_t)rel * NN * HCC;
  float* als = alsAll + (size_t)rel * NN * 4;
  float* ald = aldAll + (size_t)rel * NN * 4;

  const int tid = threadIdx.x;
  const int lane = tid & 63;
  const int w = tid >> 6;
  const int l31 = lane & 31;
  const int lg = lane >> 5;
  const int wrow = blockIdx.x * 64 + (w & 1) * 32;
  const int rb = blockIdx.x * 2 + (w & 1);
  const int ch = w >> 1;

  f32x16 acc[4];
#pragma unroll
  for (int t = 0; t < 4; ++t) acc[t] = (f32x16)(0.f);

  const int NK = KK / 16;
  // per-(rb,kst,lg) chunk: hi 256 + lo 256 shorts; wave reads 2x512B coalesced
  const short* abase = Apk + ((size_t)rb * NK * 2 + lg) * 512 + l31 * 8;
  const int qh = (ch * 2 + 0) * 2 + lg;
  const int ql = (ch * 2 + 1) * 2 + lg;

#define STAGE(kst, buf)                                                      \
  {                                                                          \
    _Pragma("unroll")                                                        \
    for (int it = 0; it < 4; ++it) {                                         \
      int so = it * 2048 + w * 512;                                          \
      __builtin_amdgcn_global_load_lds(                                      \
          (gas_t)(const void*)(Brel + (size_t)(kst) * 8192 + so + lane * 8), \
          (las_t)(void*)&Bs[buf][so], 16, 0, 0);                             \
    }                                                                        \
  }

#define LOADA(kst, AH, AL)                              \
  {                                                     \
    const short* ap_ = abase + (size_t)(kst) * 1024;    \
    AH = *(const sh8*)(ap_);                            \
    AL = *(const sh8*)(ap_ + 256);                      \
  }

#define MMBLK(buf, AH, AL)                                                            \
  {                                                                                   \
    _Pragma("unroll")                                                                 \
    for (int t = 0; t < 4; ++t) {                                                     \
      sh8 bhf = *(const sh8*)&Bs[buf][(size_t)(qh * 128 + t * 32 + l31) * 8];         \
      sh8 blf = *(const sh8*)&Bs[buf][(size_t)(ql * 128 + t * 32 + l31) * 8];         \
      acc[t] = __builtin_amdgcn_mfma_f32_32x32x16_bf16(AH, bhf, acc[t], 0, 0, 0);     \
      acc[t] = __builtin_amdgcn_mfma_f32_32x32x16_bf16(AL, bhf, acc[t], 0, 0, 0);     \
      acc[t] = __builtin_amdgcn_mfma_f32_32x32x16_bf16(AH, blf, acc[t], 0, 0, 0);     \
    }                                                                                 \
  }

  sh8 a0h, a0l, a1h, a1l;
  LOADA(0, a0h, a0l);
  STAGE(0, 0);
#pragma unroll
  for (int kst = 0; kst < NK; ++kst) {
    __syncthreads();
    if (kst + 1 < NK) {
      STAGE(kst + 1, (kst & 1) ^ 1);
      if ((kst & 1) == 0) { LOADA(kst + 1, a1h, a1l); }
      else                { LOADA(kst + 1, a0h, a0l); }
    }
    if ((kst & 1) == 0) { MMBLK(0, a0h, a0l); }
    else                { MMBLK(1, a1h, a1l); }
  }
#undef STAGE
#undef LOADA
#undef MMBLK

  // epilogue: h (fp16) store + fused alpha (2 heads per col-half)
  float asr[4], adr[4];
#pragma unroll
  for (int t = 0; t < 4; ++t) {
    int col = ch * 128 + t * 32 + l31;
    asr[t] = asf[col];
    adr[t] = adf[col];
  }
#pragma unroll
  for (int v = 0; v < 16; ++v) {
    const int rl = (v & 3) + 8 * (v >> 2) + 4 * lg;
    const int row = wrow + rl;
    const bool rok = row < M;
    float s0 = 0.f, s1 = 0.f, d0 = 0.f, d1 = 0.f;
    __half* hp = hout + (size_t)row * 256 + ch * 128 + l31;
#pragma unroll
    for (int t = 0; t < 4; ++t) {
      float dv = acc[t][v];
      if (rok) hp[t * 32] = __float2half(dv);
      if (t < 2) { s0 += dv * asr[t]; d0 += dv * adr[t]; }
      else       { s1 += dv * asr[t]; d1 += dv * adr[t]; }
    }
#pragma unroll
    for (int m = 1; m < 32; m <<= 1) {
      s0 += __shfl_xor(s0, m);
      s1 += __shfl_xor(s1, m);
      d0 += __shfl_xor(d0, m);
      d1 += __shfl_xor(d1, m);
    }
    if (rok && l31 == 0) {
      *(float2*)(als + (size_t)row * 4 + ch * 2) = make_float2(s0, s1);
      *(float2*)(ald + (size_t)row * 4 + ch * 2) = make_float2(d0, d1);
    }
  }
}

// ---------------- fused 3-relation gather core (inline weights, 4-deep) ----------------
template<bool SL>
__device__ __forceinline__ void gat_rel(int n, int head, size_t loff,
                                        const __half* __restrict__ h,
                                        const float* __restrict__ als,
                                        const float* __restrict__ ald,
                                        const int* __restrict__ rp,
                                        const int* __restrict__ cs,
                                        float& ox, float& oy, float& oz, float& ow) {
  float ad = ald[n * 4 + head];
  int rs = rp[n], re = rp[n + 1];
  float ax = 0.f, ay = 0.f, az = 0.f, aw = 0.f, wsum = 0.f;
  int i = rs;
  for (; i + 4 <= re; i += 4) {
    int s0 = cs[i], s1 = cs[i + 1], s2 = cs[i + 2], s3 = cs[i + 3];
    float al0 = als[s0 * 4 + head];
    float al1 = als[s1 * 4 + head];
    float al2 = als[s2 * 4 + head];
    float al3 = als[s3 * 4 + head];
    h4 v0 = *(const h4*)&h[(size_t)s0 * HCC + loff];
    h4 v1 = *(const h4*)&h[(size_t)s1 * HCC + loff];
    h4 v2 = *(const h4*)&h[(size_t)s2 * HCC + loff];
    h4 v3 = *(const h4*)&h[(size_t)s3 * HCC + loff];
    float w0 = edge_w(al0 + ad), w1 = edge_w(al1 + ad);
    float w2 = edge_w(al2 + ad), w3 = edge_w(al3 + ad);
    wsum += (w0 + w1) + (w2 + w3);
    ax = fmaf(w0, __half2float(v0.x), ax); ay = fmaf(w0, __half2float(v0.y), ay);
    az = fmaf(w0, __half2float(v0.z), az); aw = fmaf(w0, __half2float(v0.w), aw);
    ax = fmaf(w1, __half2float(v1.x), ax); ay = fmaf(w1, __half2float(v1.y), ay);
    az = fmaf(w1, __half2float(v1.z), az); aw = fmaf(w1, __half2float(v1.w), aw);
    ax = fmaf(w2, __half2float(v2.x), ax); ay = fmaf(w2, __half2float(v2.y), ay);
    az = fmaf(w2, __half2float(v2.z), az); aw = fmaf(w2, __half2float(v2.w), aw);
    ax = fmaf(w3, __half2float(v3.x), ax); ay = fmaf(w3, __half2float(v3.y), ay);
    az = fmaf(w3, __half2float(v3.z), az); aw = fmaf(w3, __half2float(v3.w), aw);
  }
  for (; i < re; ++i) {
    int s = cs[i];
    float w = edge_w(als[s * 4 + head] + ad);
    wsum += w;
    h4 hv = *(const h4*)&h[(size_t)s * HCC + loff];
    ax = fmaf(w, __half2float(hv.x), ax);
    ay = fmaf(w, __half2float(hv.y), ay);
    az = fmaf(w, __half2float(hv.z), az);
    aw = fmaf(w, __half2float(hv.w), aw);
  }
  if (SL) {
    float w = edge_w(als[n * 4 + head] + ad);
    wsum += w;
    h4 hv = *(const h4*)&h[(size_t)n * HCC + loff];
    ax = fmaf(w, __half2float(hv.x), ax);
    ay = fmaf(w, __half2float(hv.y), ay);
    az = fmaf(w, __half2float(hv.z), az);
    aw = fmaf(w, __half2float(hv.w), aw);
  }
  float inv = 1.0f / (wsum + 1e-16f);
  ox = fmaf(ax, inv, ox);
  oy = fmaf(ay, inv, oy);
  oz = fmaf(az, inv, oz);
  ow = fmaf(aw, inv, ow);
}

// concat layer-1 gather -> packed split-bf16 A layout for layer-2 GEMM
__global__ __launch_bounds__(256) void k_gather3c(const __half* __restrict__ h3,
                                                  const float* __restrict__ als3,
                                                  const float* __restrict__ ald3,
                                                  const int* __restrict__ rpA,
                                                  const int* __restrict__ csAll,
                                                  const float* __restrict__ bias,
                                                  short* __restrict__ o1pk) {
  int gid = blockIdx.x * blockDim.x + threadIdx.x;
  int n = gid >> 6;
  int lane = threadIdx.x & 63;
  if (n >= NN) return;
  int head = lane >> 4;
  size_t loff = (size_t)lane * 4;
  const size_t HS = (size_t)NN * HCC;
  const size_t AS = (size_t)NN * 4;
  float ox = 0.f, oy = 0.f, oz = 0.f, ow = 0.f;
  gat_rel<false>(n, head, loff, h3,          als3,          ald3,          rpA,                csAll,          ox, oy, oz, ow);
  gat_rel<true >(n, head, loff, h3 + HS,     als3 + AS,     ald3 + AS,     rpA + (NN + 1),     csAll + NE,     ox, oy, oz, ow);
  gat_rel<true >(n, head, loff, h3 + 2 * HS, als3 + 2 * AS, ald3 + 2 * AS, rpA + 2 * (NN + 1), csAll + 2 * NE, ox, oy, oz, ow);
  float4 b0 = *(const float4*)&bias[lane * 4];
  float4 b1 = *(const float4*)&bias[HCC + lane * 4];
  float4 b2 = *(const float4*)&bias[2 * HCC + lane * 4];
  float vv[4];
  vv[0] = fmaxf(ox + b0.x + b1.x + b2.x, 0.f);
  vv[1] = fmaxf(oy + b0.y + b1.y + b2.y, 0.f);
  vv[2] = fmaxf(oz + b0.z + b1.z + b2.z, 0.f);
  vv[3] = fmaxf(ow + b0.w + b1.w + b2.w, 0.f);
  s4 hv, lv;
  short* hp = (short*)&hv;
  short* lp = (short*)&lv;
#pragma unroll
  for (int j = 0; j < 4; ++j) {
    unsigned short hb = bf_rne(vv[j]);
    float hf = __uint_as_float(((unsigned)hb) << 16);
    hp[j] = (short)hb;
    lp[j] = (short)bf_rne(vv[j] - hf);
  }
  // packed A layout: k = 4*lane+j -> kst=lane>>2, lg=(lane>>1)&1, kj0=(lane&1)*4
  int rb = n >> 5, l31 = n & 31;
  int kst = lane >> 2, lgb = (lane >> 1) & 1, kj0 = (lane & 1) * 4;
  size_t base = ((size_t)(rb * 16 + kst) * 2 + lgb) * 512;
  *(s4*)&o1pk[base + l31 * 8 + kj0] = hv;
  *(s4*)&o1pk[base + 256 + l31 * 8 + kj0] = lv;
}

// layer-2 gather + fused final: outp[n,64] = relu(mean + biases) @ Wl + bl
__global__ __launch_bounds__(256) void k_gather3f(const __half* __restrict__ h3,
                                                  const float* __restrict__ als3,
                                                  const float* __restrict__ ald3,
                                                  const int* __restrict__ rpA,
                                                  const int* __restrict__ csAll,
                                                  const float* __restrict__ bias,
                                                  const float* __restrict__ Wl,
                                                  const float* __restrict__ bl,
                                                  float* __restrict__ outp) {
  __shared__ float Ws[64 * 64];
  for (int i = threadIdx.x; i < 4096; i += 256) Ws[i] = Wl[i];
  __syncthreads();  // safe: grid covers exactly NN*64 threads
  int gid = blockIdx.x * blockDim.x + threadIdx.x;
  int n = gid >> 6;
  int lane = threadIdx.x & 63;
  if (n >= NN) return;
  int head = lane >> 4;
  size_t loff = (size_t)lane * 4;
  const size_t HS = (size_t)NN * HCC;
  const size_t AS = (size_t)NN * 4;
  float ox = 0.f, oy = 0.f, oz = 0.f, ow = 0.f;
  gat_rel<false>(n, head, loff, h3,          als3,          ald3,          rpA,                csAll,          ox, oy, oz, ow);
  gat_rel<true >(n, head, loff, h3 + HS,     als3 + AS,     ald3 + AS,     rpA + (NN + 1),     csAll + NE,     ox, oy, oz, ow);
  gat_rel<true >(n, head, loff, h3 + 2 * HS, als3 + 2 * AS, ald3 + 2 * AS, rpA + 2 * (NN + 1), csAll + 2 * NE, ox, oy, oz, ow);
  ox += __shfl_xor(ox, 16); oy += __shfl_xor(oy, 16);
  oz += __shfl_xor(oz, 16); ow += __shfl_xor(ow, 16);
  ox += __shfl_xor(ox, 32); oy += __shfl_xor(oy, 32);
  oz += __shfl_xor(oz, 32); ow += __shfl_xor(ow, 32);
  int q0 = lane & 15;
  float4 b0 = *(const float4*)&bias[q0 * 4];
  float4 b1 = *(const float4*)&bias[OC + q0 * 4];
  float4 b2 = *(const float4*)&bias[2 * OC + q0 * 4];
  float x0 = fmaxf(0.25f * ox + b0.x + b1.x + b2.x, 0.f);
  float x1 = fmaxf(0.25f * oy + b0.y + b1.y + b2.y, 0.f);
  float x2 = fmaxf(0.25f * oz + b0.z + b1.z + b2.z, 0.f);
  float x3 = fmaxf(0.25f * ow + b0.w + b1.w + b2.w, 0.f);
  float acc = bl[lane];
#pragma unroll
  for (int q = 0; q < 16; ++q) {
    float xa = __shfl(x0, q);
    float xb = __shfl(x1, q);
    float xc = __shfl(x2, q);
    float xd = __shfl(x3, q);
    acc = fmaf(xa, Ws[(4 * q + 0) * 64 + lane], acc);
    acc = fmaf(xb, Ws[(4 * q + 1) * 64 + lane], acc);
    acc = fmaf(xc, Ws[(4 * q + 2) * 64 + lane], acc);
    acc = fmaf(xd, Ws[(4 * q + 3) * 64 + lane], acc);
  }
  outp[(size_t)n * OC + lane] = acc;
}

extern "C" void kernel_launch(void* const* d_in, const int* in_sizes, int n_in,
                              void* d_out, int out_size, void* d_ws, size_t ws_size,
                              hipStream_t stream) {
  const float* x   = (const float*)d_in[0];
  const int* e_b   = (const int*)d_in[1];
  const int* e_sp  = (const int*)d_in[2];
  const int* e_si  = (const int*)d_in[3];
  const float* W1  = (const float*)d_in[4];
  const float* a1s = (const float*)d_in[5];
  const float* a1d = (const float*)d_in[6];
  const float* b1  = (const float*)d_in[7];
  const float* W2  = (const float*)d_in[8];
  const float* a2s = (const float*)d_in[9];
  const float* a2d = (const float*)d_in[10];
  const float* b2  = (const float*)d_in[11];
  const float* Wl  = (const float*)d_in[12];
  const float* bl  = (const float*)d_in[13];
  float* out = (float*)d_out;

  char* ws = (char*)d_ws;
  size_t off = 0;
  auto alloc = [&](size_t b) {
    char* p = ws + off;
    off += (b + 255) & ~(size_t)255;
    return p;
  };
  __half* h3  = (__half*)alloc((size_t)3 * NN * HCC * 2);     // 76.8 MB
  short* o1pk = (short*)alloc((size_t)RB1 * 16 * 1024 * 2);   // 51.2 MB packed layer-2 A
  short* xpk  = (short*)alloc((size_t)RB1 * 8 * 1024 * 2);    // 25.6 MB packed layer-1 A
  float* als3 = (float*)alloc((size_t)3 * NN * 4 * 4);
  float* ald3 = (float*)alloc((size_t)3 * NN * 4 * 4);
  int* deg3    = (int*)alloc((size_t)NT3 * 4);
  int* cursor3 = (int*)alloc((size_t)NT3 * 4);
  int* rpA     = (int*)alloc((size_t)3 * (NN + 1) * 4);
  int* bsum    = (int*)alloc(256 * 4);
  int* boffs   = (int*)alloc(256 * 4);
  short* Wc1   = (short*)alloc((size_t)3 * 4 * FIN * 128 * 2);
  short* Wc2   = (short*)alloc((size_t)3 * 4 * HCC * 128 * 2);
  int* csAll   = (int*)alloc((size_t)3 * NE * 4);

  const int* edges[3] = {e_b, e_sp, e_si};

  // weight pre-split + x pre-pack (tiny)
  k_prep<FIN><<<(3 * FIN * 256 + 255) / 256, 256, 0, stream>>>(W1, Wc1);
  k_prep<HCC><<<(3 * HCC * 256 + 255) / 256, 256, 0, stream>>>(W2, Wc2);
  k_split<<<(NN * 32 + 255) / 256, 256, 0, stream>>>(x, xpk);

  // CSR build
  hipMemsetAsync(deg3, 0, (size_t)NT3 * 4, stream);
  k_hist3<<<2048, 256, 0, stream>>>(e_b, e_sp, e_si, deg3);
  const int NB = (NT3 + 1023) / 1024;  // 147
  k_bsum<<<NB, 1024, 0, stream>>>(deg3, bsum);
  k_scan2<<<1, 256, 0, stream>>>(bsum, boffs, NB);
  k_rowptr<<<NB, 1024, 0, stream>>>(deg3, boffs, rpA, cursor3);
  for (int r = 0; r < 3; ++r)
    k_scatter<<<1024, 256, 0, stream>>>(edges[r], edges[r] + NE, cursor3 + r * NN,
                                        csAll + (size_t)r * NE, NE);

  const int gblocks = (NN + 63) / 64;   // 782
  const int ablocks = (NN * 64) / 256;  // 12500

  // layer 1
  k_mgemm<FIN><<<dim3(gblocks, 3), 256, 0, stream>>>(
      xpk, Wc1, a1s, a1d, h3, als3, ald3, NN);
  k_gather3c<<<ablocks, 256, 0, stream>>>(
      h3, als3, ald3, rpA, csAll, b1, o1pk);

  // layer 2 (+ fused final linear)
  k_mgemm<HCC><<<dim3(gblocks, 3), 256, 0, stream>>>(
      o1pk, Wc2, a2s, a2d, h3, als3, ald3, NN);
  k_gather3f<<<ablocks, 256, 0, stream>>>(
      h3, als3, ald3, rpA, csAll, b2, Wl, bl, out);
}

// Round 13
// 860.545 us; speedup vs baseline: 1.0163x; 1.0163x over previous
//
#include <hip/hip_runtime.h>
#include <hip/hip_bf16.h>
#include <hip/hip_fp16.h>

#define NN 50000
#define NE 800000
#define FIN 128
#define HCC 256   // HEADS*HID
#define OC 64
#define NSL 0.2f
#define NT3 (3 * NN)

typedef __attribute__((ext_vector_type(8))) short sh8;
typedef __attribute__((ext_vector_type(16))) float f32x16;

struct __attribute__((aligned(8))) h4 { __half x, y, z, w; };
struct __attribute__((aligned(8))) s4 { short x, y, z, w; };

typedef const __attribute__((address_space(1))) unsigned int* gas_t;
typedef __attribute__((address_space(3))) unsigned int* las_t;

__device__ __forceinline__ unsigned short bf_rne(float f) {
  unsigned u = __float_as_uint(f);
  u += 0x7FFF + ((u >> 16) & 1);
  return (unsigned short)(u >> 16);
}

__device__ __forceinline__ float edge_w(float lg) {
  lg = (lg > 0.f) ? lg : NSL * lg;
  return __expf(lg);
}

// -------- weight pre-split into per-K-step contiguous chunks --------
// W:[3][KK][256] fp32 -> out:[3][kst][q(8)][c(128)][kj(8)] bf16
template<int KK>
__global__ __launch_bounds__(256) void k_prep(const float* __restrict__ W,
                                              short* __restrict__ out) {
  int i = blockIdx.x * 256 + threadIdx.x;
  if (i >= 3 * KK * 256) return;
  int r = i / (KK * 256);
  int rem = i - r * KK * 256;
  int k = rem >> 8;
  int n = rem & 255;
  float f = W[i];
  unsigned short hb = bf_rne(f);
  float hf = __uint_as_float(((unsigned)hb) << 16);
  unsigned short lb = bf_rne(f - hf);
  int cb = n >> 7, c = n & 127;
  int kst = k >> 4, p = (k >> 3) & 1, kj = k & 7;
  size_t base = (size_t)r * 4 * KK * 128;
  size_t oh = base + ((size_t)(kst * 8 + (cb * 2 + 0) * 2 + p) * 128 + c) * 8 + kj;
  size_t ol = base + ((size_t)(kst * 8 + (cb * 2 + 1) * 2 + p) * 128 + c) * 8 + kj;
  out[oh] = (short)hb;
  out[ol] = (short)lb;
}

// -------- x fp32 -> bf16 hi/lo --------
__global__ __launch_bounds__(256) void k_split(const float* __restrict__ x,
                                               short* __restrict__ xhi,
                                               short* __restrict__ xlo) {
  int i = blockIdx.x * 256 + threadIdx.x;
  if (i >= NN * FIN / 4) return;
  float4 v = ((const float4*)x)[i];
  s4 h, l;
  float f, hf;
  f = v.x; h.x = (short)bf_rne(f); hf = __uint_as_float(((unsigned)(unsigned short)h.x) << 16); l.x = (short)bf_rne(f - hf);
  f = v.y; h.y = (short)bf_rne(f); hf = __uint_as_float(((unsigned)(unsigned short)h.y) << 16); l.y = (short)bf_rne(f - hf);
  f = v.z; h.z = (short)bf_rne(f); hf = __uint_as_float(((unsigned)(unsigned short)h.z) << 16); l.z = (short)bf_rne(f - hf);
  f = v.w; h.w = (short)bf_rne(f); hf = __uint_as_float(((unsigned)(unsigned short)h.w) << 16); l.w = (short)bf_rne(f - hf);
  ((s4*)xhi)[i] = h;
  ((s4*)xlo)[i] = l;
}

// ---------------- CSR build ----------------
__global__ void k_hist3(const int* __restrict__ e0, const int* __restrict__ e1,
                        const int* __restrict__ e2, int* __restrict__ deg3) {
  int i = blockIdx.x * blockDim.x + threadIdx.x;
  int st = gridDim.x * blockDim.x;
  for (; i < 3 * NE; i += st) {
    int rel = i / NE;
    int j = i - rel * NE;
    const int* e = (rel == 0) ? e0 : ((rel == 1) ? e1 : e2);
    atomicAdd(&deg3[rel * NN + e[NE + j]], 1);
  }
}

__global__ __launch_bounds__(1024) void k_bsum(const int* __restrict__ deg3,
                                               int* __restrict__ bsum) {
  __shared__ int s[1024];
  int t = threadIdx.x;
  int i = blockIdx.x * 1024 + t;
  s[t] = (i < NT3) ? deg3[i] : 0;
  __syncthreads();
  for (int off = 512; off > 0; off >>= 1) {
    if (t < off) s[t] += s[t + off];
    __syncthreads();
  }
  if (t == 0) bsum[blockIdx.x] = s[0];
}

__global__ __launch_bounds__(256) void k_scan2(const int* __restrict__ bsum,
                                               int* __restrict__ boffs, int nb) {
  __shared__ int s[256];
  int t = threadIdx.x;
  int v = (t < nb) ? bsum[t] : 0;
  s[t] = v;
  __syncthreads();
  for (int off = 1; off < 256; off <<= 1) {
    int x = (t >= off) ? s[t - off] : 0;
    __syncthreads();
    s[t] += x;
    __syncthreads();
  }
  if (t < nb) boffs[t] = s[t] - v;  // exclusive
}

__global__ __launch_bounds__(1024) void k_rowptr(const int* __restrict__ deg3,
                                                 const int* __restrict__ boffs,
                                                 int* __restrict__ rpA,
                                                 int* __restrict__ cursor3) {
  __shared__ int s[1024];
  int t = threadIdx.x;
  int i = blockIdx.x * 1024 + t;
  int d = (i < NT3) ? deg3[i] : 0;
  s[t] = d;
  __syncthreads();
  for (int off = 1; off < 1024; off <<= 1) {
    int x = (t >= off) ? s[t - off] : 0;
    __syncthreads();
    s[t] += x;
    __syncthreads();
  }
  if (i < NT3) {
    int excl = boffs[blockIdx.x] + s[t] - d;
    int r = (i < NN) ? 0 : ((i < 2 * NN) ? 1 : 2);
    int n = i - r * NN;
    int val = excl - r * NE;
    rpA[r * (NN + 1) + n] = val;
    cursor3[i] = val;
  }
  if (blockIdx.x == 0 && t < 3) rpA[t * (NN + 1) + NN] = NE;
}

// one relation per launch: random-write region (3.2 MB) stays L2-resident
__global__ void k_scatter(const int* __restrict__ srcv, const int* __restrict__ dstv,
                          int* __restrict__ cursor, int* __restrict__ csr_src, int n) {
  int i = blockIdx.x * blockDim.x + threadIdx.x;
  int st = gridDim.x * blockDim.x;
  for (; i < n; i += st) {
    int pos = atomicAdd(&cursor[dstv[i]], 1);
    csr_src[pos] = srcv[i];
  }
}

// -------- split-bf16 MFMA GEMM (32x32x16), LDS-staged B, h-store-only epilogue ----
template<int KK>
__global__ __launch_bounds__(256) void k_mgemm(const short* __restrict__ Ahi,
                                               const short* __restrict__ Alo,
                                               const short* __restrict__ BcAll,
                                               __half* __restrict__ houtAll, int M) {
  __shared__ short Bs[2][8192];  // 2 x 16 KB
  const int rel = blockIdx.y;
  const short* Brel = BcAll + (size_t)rel * 4 * KK * 128;
  __half* hout = houtAll + (size_t)rel * NN * HCC;

  const int tid = threadIdx.x;
  const int lane = tid & 63;
  const int w = tid >> 6;
  const int l31 = lane & 31;
  const int lg = lane >> 5;
  const int wrow = blockIdx.x * 64 + (w & 1) * 32;
  const int ch = w >> 1;

  f32x16 acc[4];
#pragma unroll
  for (int t = 0; t < 4; ++t) acc[t] = (f32x16)(0.f);

  const int r = wrow + l31;
  const bool aok = r < M;
  const short* ahp = Ahi + (size_t)r * KK;
  const short* alp = Alo + (size_t)r * KK;
  const int qh = (ch * 2 + 0) * 2 + lg;
  const int ql = (ch * 2 + 1) * 2 + lg;

  const int NK = KK / 16;

#define STAGE(kst, buf)                                                      \
  {                                                                          \
    _Pragma("unroll")                                                        \
    for (int it = 0; it < 4; ++it) {                                         \
      int so = it * 2048 + w * 512;                                          \
      __builtin_amdgcn_global_load_lds(                                      \
          (gas_t)(const void*)(Brel + (size_t)(kst) * 8192 + so + lane * 8), \
          (las_t)(void*)&Bs[buf][so], 16, 0, 0);                             \
    }                                                                        \
  }

#define LOADA(kst, AH, AL)                 \
  {                                        \
    const int k0 = (kst) * 16 + lg * 8;    \
    AH = (sh8){0, 0, 0, 0, 0, 0, 0, 0};    \
    AL = AH;                               \
    if (aok) {                             \
      AH = *(const sh8*)(ahp + k0);        \
      AL = *(const sh8*)(alp + k0);        \
    }                                      \
  }

#define MMBLK(buf, AH, AL)                                                            \
  {                                                                                   \
    _Pragma("unroll")                                                                 \
    for (int t = 0; t < 4; ++t) {                                                     \
      sh8 bhf = *(const sh8*)&Bs[buf][(size_t)(qh * 128 + t * 32 + l31) * 8];         \
      sh8 blf = *(const sh8*)&Bs[buf][(size_t)(ql * 128 + t * 32 + l31) * 8];         \
      acc[t] = __builtin_amdgcn_mfma_f32_32x32x16_bf16(AH, bhf, acc[t], 0, 0, 0);     \
      acc[t] = __builtin_amdgcn_mfma_f32_32x32x16_bf16(AL, bhf, acc[t], 0, 0, 0);     \
      acc[t] = __builtin_amdgcn_mfma_f32_32x32x16_bf16(AH, blf, acc[t], 0, 0, 0);     \
    }                                                                                 \
  }

  sh8 a0h, a0l, a1h, a1l;
  LOADA(0, a0h, a0l);
  STAGE(0, 0);
#pragma unroll
  for (int kst = 0; kst < NK; ++kst) {
    __syncthreads();
    if (kst + 1 < NK) {
      STAGE(kst + 1, (kst & 1) ^ 1);
      if ((kst & 1) == 0) { LOADA(kst + 1, a1h, a1l); }
      else                { LOADA(kst + 1, a0h, a0l); }
    }
    if ((kst & 1) == 0) { MMBLK(0, a0h, a0l); }
    else                { MMBLK(1, a1h, a1l); }
  }
#undef STAGE
#undef LOADA
#undef MMBLK

  // epilogue: h (fp16) store only
#pragma unroll
  for (int v = 0; v < 16; ++v) {
    const int rl = (v & 3) + 8 * (v >> 2) + 4 * lg;
    const int row = wrow + rl;
    if (row < M) {
      __half* hp = hout + (size_t)row * 256 + ch * 128 + l31;
#pragma unroll
      for (int t = 0; t < 4; ++t) hp[t * 32] = __float2half(acc[t][v]);
    }
  }
}

// -------- alpha: one wave per (rel,node); coalesced 512B row read --------
__global__ __launch_bounds__(256) void k_alpha3(const __half* __restrict__ h3,
                                                const float* __restrict__ asAll,
                                                const float* __restrict__ adAll,
                                                float* __restrict__ als3,
                                                float* __restrict__ ald3) {
  int wid = (blockIdx.x * 256 + threadIdx.x) >> 6;
  int lane = threadIdx.x & 63;
  if (wid >= NT3) return;
  int rel = wid / NN;
  int n = wid - rel * NN;
  h4 hv4 = *(const h4*)&h3[((size_t)rel * NN + n) * HCC + lane * 4];
  float hx = __half2float(hv4.x), hy = __half2float(hv4.y);
  float hz = __half2float(hv4.z), hw = __half2float(hv4.w);
  float4 s4v = *(const float4*)&asAll[rel * HCC + lane * 4];
  float4 d4v = *(const float4*)&adAll[rel * HCC + lane * 4];
  float ss = hx * s4v.x + hy * s4v.y + hz * s4v.z + hw * s4v.w;
  float sd = hx * d4v.x + hy * d4v.y + hz * d4v.z + hw * d4v.w;
#pragma unroll
  for (int m = 1; m < 16; m <<= 1) {
    ss += __shfl_xor(ss, m);
    sd += __shfl_xor(sd, m);
  }
  if ((lane & 15) == 0) {
    int head = lane >> 4;
    als3[((size_t)rel * NN + n) * 4 + head] = ss;
    ald3[((size_t)rel * NN + n) * 4 + head] = sd;
  }
}

// ---------------- fused 3-relation gather core (inline weights, 4-deep) ----------------
template<bool SL>
__device__ __forceinline__ void gat_rel(int n, int head, size_t loff,
                                        const __half* __restrict__ h,
                                        const float* __restrict__ als,
                                        const float* __restrict__ ald,
                                        const int* __restrict__ rp,
                                        const int* __restrict__ cs,
                                        float& ox, float& oy, float& oz, float& ow) {
  float ad = ald[n * 4 + head];
  int rs = rp[n], re = rp[n + 1];
  float ax = 0.f, ay = 0.f, az = 0.f, aw = 0.f, wsum = 0.f;
  int i = rs;
  for (; i + 4 <= re; i += 4) {
    int s0 = cs[i], s1 = cs[i + 1], s2 = cs[i + 2], s3 = cs[i + 3];
    float al0 = als[s0 * 4 + head];
    float al1 = als[s1 * 4 + head];
    float al2 = als[s2 * 4 + head];
    float al3 = als[s3 * 4 + head];
    h4 v0 = *(const h4*)&h[(size_t)s0 * HCC + loff];
    h4 v1 = *(const h4*)&h[(size_t)s1 * HCC + loff];
    h4 v2 = *(const h4*)&h[(size_t)s2 * HCC + loff];
    h4 v3 = *(const h4*)&h[(size_t)s3 * HCC + loff];
    float w0 = edge_w(al0 + ad), w1 = edge_w(al1 + ad);
    float w2 = edge_w(al2 + ad), w3 = edge_w(al3 + ad);
    wsum += (w0 + w1) + (w2 + w3);
    ax = fmaf(w0, __half2float(v0.x), ax); ay = fmaf(w0, __half2float(v0.y), ay);
    az = fmaf(w0, __half2float(v0.z), az); aw = fmaf(w0, __half2float(v0.w), aw);
    ax = fmaf(w1, __half2float(v1.x), ax); ay = fmaf(w1, __half2float(v1.y), ay);
    az = fmaf(w1, __half2float(v1.z), az); aw = fmaf(w1, __half2float(v1.w), aw);
    ax = fmaf(w2, __half2float(v2.x), ax); ay = fmaf(w2, __half2float(v2.y), ay);
    az = fmaf(w2, __half2float(v2.z), az); aw = fmaf(w2, __half2float(v2.w), aw);
    ax = fmaf(w3, __half2float(v3.x), ax); ay = fmaf(w3, __half2float(v3.y), ay);
    az = fmaf(w3, __half2float(v3.z), az); aw = fmaf(w3, __half2float(v3.w), aw);
  }
  for (; i < re; ++i) {
    int s = cs[i];
    float w = edge_w(als[s * 4 + head] + ad);
    wsum += w;
    h4 hv = *(const h4*)&h[(size_t)s * HCC + loff];
    ax = fmaf(w, __half2float(hv.x), ax);
    ay = fmaf(w, __half2float(hv.y), ay);
    az = fmaf(w, __half2float(hv.z), az);
    aw = fmaf(w, __half2float(hv.w), aw);
  }
  if (SL) {
    float w = edge_w(als[n * 4 + head] + ad);
    wsum += w;
    h4 hv = *(const h4*)&h[(size_t)n * HCC + loff];
    ax = fmaf(w, __half2float(hv.x), ax);
    ay = fmaf(w, __half2float(hv.y), ay);
    az = fmaf(w, __half2float(hv.z), az);
    aw = fmaf(w, __half2float(hv.w), aw);
  }
  float inv = 1.0f / (wsum + 1e-16f);
  ox = fmaf(ax, inv, ox);
  oy = fmaf(ay, inv, oy);
  oz = fmaf(az, inv, oz);
  ow = fmaf(aw, inv, ow);
}

// concat layer-1 gather: o1hi/o1lo[n,256] = split-bf16 relu(sum_r gat + sum_r bias)
__global__ __launch_bounds__(256) void k_gather3c(const __half* __restrict__ h3,
                                                  const float* __restrict__ als3,
                                                  const float* __restrict__ ald3,
                                                  const int* __restrict__ rpA,
                                                  const int* __restrict__ csAll,
                                                  const float* __restrict__ bias,
                                                  short* __restrict__ o1hi,
                                                  short* __restrict__ o1lo) {
  int gid = blockIdx.x * blockDim.x + threadIdx.x;
  int n = gid >> 6;
  int lane = threadIdx.x & 63;
  if (n >= NN) return;
  int head = lane >> 4;
  size_t loff = (size_t)lane * 4;
  const size_t HS = (size_t)NN * HCC;
  const size_t AS = (size_t)NN * 4;
  float ox = 0.f, oy = 0.f, oz = 0.f, ow = 0.f;
  gat_rel<false>(n, head, loff, h3,          als3,          ald3,          rpA,                csAll,          ox, oy, oz, ow);
  gat_rel<true >(n, head, loff, h3 + HS,     als3 + AS,     ald3 + AS,     rpA + (NN + 1),     csAll + NE,     ox, oy, oz, ow);
  gat_rel<true >(n, head, loff, h3 + 2 * HS, als3 + 2 * AS, ald3 + 2 * AS, rpA + 2 * (NN + 1), csAll + 2 * NE, ox, oy, oz, ow);
  float4 b0 = *(const float4*)&bias[lane * 4];
  float4 b1 = *(const float4*)&bias[HCC + lane * 4];
  float4 b2 = *(const float4*)&bias[2 * HCC + lane * 4];
  float vv[4];
  vv[0] = fmaxf(ox + b0.x + b1.x + b2.x, 0.f);
  vv[1] = fmaxf(oy + b0.y + b1.y + b2.y, 0.f);
  vv[2] = fmaxf(oz + b0.z + b1.z + b2.z, 0.f);
  vv[3] = fmaxf(ow + b0.w + b1.w + b2.w, 0.f);
  s4 hv, lv;
  short* hp = (short*)&hv;
  short* lp = (short*)&lv;
#pragma unroll
  for (int j = 0; j < 4; ++j) {
    unsigned short hb = bf_rne(vv[j]);
    float hf = __uint_as_float(((unsigned)hb) << 16);
    hp[j] = (short)hb;
    lp[j] = (short)bf_rne(vv[j] - hf);
  }
  *(s4*)&o1hi[(size_t)n * HCC + loff] = hv;
  *(s4*)&o1lo[(size_t)n * HCC + loff] = lv;
}

// layer-2 gather + fused final: outp[n,64] = relu(mean + biases) @ Wl + bl
__global__ __launch_bounds__(256) void k_gather3f(const __half* __restrict__ h3,
                                                  const float* __restrict__ als3,
                                                  const float* __restrict__ ald3,
                                                  const int* __restrict__ rpA,
                                                  const int* __restrict__ csAll,
                                                  const float* __restrict__ bias,
                                                  const float* __restrict__ Wl,
                                                  const float* __restrict__ bl,
                                                  float* __restrict__ outp) {
  __shared__ float Ws[64 * 64];
  for (int i = threadIdx.x; i < 4096; i += 256) Ws[i] = Wl[i];
  __syncthreads();  // safe: grid covers exactly NN*64 threads
  int gid = blockIdx.x * blockDim.x + threadIdx.x;
  int n = gid >> 6;
  int lane = threadIdx.x & 63;
  if (n >= NN) return;
  int head = lane >> 4;
  size_t loff = (size_t)lane * 4;
  const size_t HS = (size_t)NN * HCC;
  const size_t AS = (size_t)NN * 4;
  float ox = 0.f, oy = 0.f, oz = 0.f, ow = 0.f;
  gat_rel<false>(n, head, loff, h3,          als3,          ald3,          rpA,                csAll,          ox, oy, oz, ow);
  gat_rel<true >(n, head, loff, h3 + HS,     als3 + AS,     ald3 + AS,     rpA + (NN + 1),     csAll + NE,     ox, oy, oz, ow);
  gat_rel<true >(n, head, loff, h3 + 2 * HS, als3 + 2 * AS, ald3 + 2 * AS, rpA + 2 * (NN + 1), csAll + 2 * NE, ox, oy, oz, ow);
  ox += __shfl_xor(ox, 16); oy += __shfl_xor(oy, 16);
  oz += __shfl_xor(oz, 16); ow += __shfl_xor(ow, 16);
  ox += __shfl_xor(ox, 32); oy += __shfl_xor(oy, 32);
  oz += __shfl_xor(oz, 32); ow += __shfl_xor(ow, 32);
  int q0 = lane & 15;
  float4 b0 = *(const float4*)&bias[q0 * 4];
  float4 b1 = *(const float4*)&bias[OC + q0 * 4];
  float4 b2 = *(const float4*)&bias[2 * OC + q0 * 4];
  float x0 = fmaxf(0.25f * ox + b0.x + b1.x + b2.x, 0.f);
  float x1 = fmaxf(0.25f * oy + b0.y + b1.y + b2.y, 0.f);
  float x2 = fmaxf(0.25f * oz + b0.z + b1.z + b2.z, 0.f);
  float x3 = fmaxf(0.25f * ow + b0.w + b1.w + b2.w, 0.f);
  float acc = bl[lane];
#pragma unroll
  for (int q = 0; q < 16; ++q) {
    float xa = __shfl(x0, q);
    float xb = __shfl(x1, q);
    float xc = __shfl(x2, q);
    float xd = __shfl(x3, q);
    acc = fmaf(xa, Ws[(4 * q + 0) * 64 + lane], acc);
    acc = fmaf(xb, Ws[(4 * q + 1) * 64 + lane], acc);
    acc = fmaf(xc, Ws[(4 * q + 2) * 64 + lane], acc);
    acc = fmaf(xd, Ws[(4 * q + 3) * 64 + lane], acc);
  }
  outp[(size_t)n * OC + lane] = acc;
}

extern "C" void kernel_launch(void* const* d_in, const int* in_sizes, int n_in,
                              void* d_out, int out_size, void* d_ws, size_t ws_size,
                              hipStream_t stream) {
  const float* x   = (const float*)d_in[0];
  const int* e_b   = (const int*)d_in[1];
  const int* e_sp  = (const int*)d_in[2];
  const int* e_si  = (const int*)d_in[3];
  const float* W1  = (const float*)d_in[4];
  const float* a1s = (const float*)d_in[5];
  const float* a1d = (const float*)d_in[6];
  const float* b1  = (const float*)d_in[7];
  const float* W2  = (const float*)d_in[8];
  const float* a2s = (const float*)d_in[9];
  const float* a2d = (const float*)d_in[10];
  const float* b2  = (const float*)d_in[11];
  const float* Wl  = (const float*)d_in[12];
  const float* bl  = (const float*)d_in[13];
  float* out = (float*)d_out;

  char* ws = (char*)d_ws;
  size_t off = 0;
  auto alloc = [&](size_t b) {
    char* p = ws + off;
    off += (b + 255) & ~(size_t)255;
    return p;
  };
  __half* h3  = (__half*)alloc((size_t)3 * NN * HCC * 2);   // 76.8 MB
  short* o1hi = (short*)alloc((size_t)NN * HCC * 2);        // 25.6 MB
  short* o1lo = (short*)alloc((size_t)NN * HCC * 2);        // 25.6 MB
  short* xhi  = (short*)alloc((size_t)NN * FIN * 2);        // 12.8 MB
  short* xlo  = (short*)alloc((size_t)NN * FIN * 2);        // 12.8 MB
  float* als3 = (float*)alloc((size_t)3 * NN * 4 * 4);
  float* ald3 = (float*)alloc((size_t)3 * NN * 4 * 4);
  int* deg3    = (int*)alloc((size_t)NT3 * 4);
  int* cursor3 = (int*)alloc((size_t)NT3 * 4);
  int* rpA     = (int*)alloc((size_t)3 * (NN + 1) * 4);
  int* bsum    = (int*)alloc(256 * 4);
  int* boffs   = (int*)alloc(256 * 4);
  short* Wc1   = (short*)alloc((size_t)3 * 4 * FIN * 128 * 2);
  short* Wc2   = (short*)alloc((size_t)3 * 4 * HCC * 128 * 2);
  int* csAll   = (int*)alloc((size_t)3 * NE * 4);

  const int* edges[3] = {e_b, e_sp, e_si};

  // weight pre-split + x pre-split (tiny)
  k_prep<FIN><<<(3 * FIN * 256 + 255) / 256, 256, 0, stream>>>(W1, Wc1);
  k_prep<HCC><<<(3 * HCC * 256 + 255) / 256, 256, 0, stream>>>(W2, Wc2);
  k_split<<<(NN * FIN / 4 + 255) / 256, 256, 0, stream>>>(x, xhi, xlo);

  // CSR build
  hipMemsetAsync(deg3, 0, (size_t)NT3 * 4, stream);
  k_hist3<<<2048, 256, 0, stream>>>(e_b, e_sp, e_si, deg3);
  const int NB = (NT3 + 1023) / 1024;  // 147
  k_bsum<<<NB, 1024, 0, stream>>>(deg3, bsum);
  k_scan2<<<1, 256, 0, stream>>>(bsum, boffs, NB);
  k_rowptr<<<NB, 1024, 0, stream>>>(deg3, boffs, rpA, cursor3);
  for (int r = 0; r < 3; ++r)
    k_scatter<<<1024, 256, 0, stream>>>(edges[r], edges[r] + NE, cursor3 + r * NN,
                                        csAll + (size_t)r * NE, NE);

  const int gblocks = (NN + 63) / 64;   // 782
  const int ablocks = (NN * 64) / 256;  // 12500
  const int wblocks = (NT3 + 3) / 4;    // one wave per (rel,node)

  // layer 1
  k_mgemm<FIN><<<dim3(gblocks, 3), 256, 0, stream>>>(xhi, xlo, Wc1, h3, NN);
  k_alpha3<<<wblocks, 256, 0, stream>>>(h3, a1s, a1d, als3, ald3);
  k_gather3c<<<ablocks, 256, 0, stream>>>(
      h3, als3, ald3, rpA, csAll, b1, o1hi, o1lo);

  // layer 2 (+ fused final linear)
  k_mgemm<HCC><<<dim3(gblocks, 3), 256, 0, stream>>>(o1hi, o1lo, Wc2, h3, NN);
  k_alpha3<<<wblocks, 256, 0, stream>>>(h3, a2s, a2d, als3, ald3);
  k_gather3f<<<ablocks, 256, 0, stream>>>(
      h3, als3, ald3, rpA, csAll, b2, Wl, bl, out);
}

// Round 14
// 833.679 us; speedup vs baseline: 1.0491x; 1.0322x over previous
//
#include <hip/hip_runtime.h>
#include <hip/hip_bf16.h>
#include <hip/hip_fp16.h>

#define NN 50000
#define NE 800000
#define FIN 128
#define HCC 256   // HEADS*HID
#define OC 64
#define NSL 0.2f
#define NT3 (3 * NN)

typedef __attribute__((ext_vector_type(8))) short sh8;
typedef __attribute__((ext_vector_type(16))) float f32x16;

struct __attribute__((aligned(8))) h4 { __half x, y, z, w; };
struct __attribute__((aligned(8))) s4 { short x, y, z, w; };

typedef const __attribute__((address_space(1))) unsigned int* gas_t;
typedef __attribute__((address_space(3))) unsigned int* las_t;

__device__ __forceinline__ unsigned short bf_rne(float f) {
  unsigned u = __float_as_uint(f);
  u += 0x7FFF + ((u >> 16) & 1);
  return (unsigned short)(u >> 16);
}

__device__ __forceinline__ float edge_w(float lg) {
  lg = (lg > 0.f) ? lg : NSL * lg;
  return __expf(lg);
}

// -------- weight pre-split into per-K-step contiguous chunks --------
// W:[3][KK][256] fp32 -> out:[3][kst][q(8)][c(128)][kj(8)] bf16
template<int KK>
__global__ __launch_bounds__(256) void k_prep(const float* __restrict__ W,
                                              short* __restrict__ out) {
  int i = blockIdx.x * 256 + threadIdx.x;
  if (i >= 3 * KK * 256) return;
  int r = i / (KK * 256);
  int rem = i - r * KK * 256;
  int k = rem >> 8;
  int n = rem & 255;
  float f = W[i];
  unsigned short hb = bf_rne(f);
  float hf = __uint_as_float(((unsigned)hb) << 16);
  unsigned short lb = bf_rne(f - hf);
  int cb = n >> 7, c = n & 127;
  int kst = k >> 4, p = (k >> 3) & 1, kj = k & 7;
  size_t base = (size_t)r * 4 * KK * 128;
  size_t oh = base + ((size_t)(kst * 8 + (cb * 2 + 0) * 2 + p) * 128 + c) * 8 + kj;
  size_t ol = base + ((size_t)(kst * 8 + (cb * 2 + 1) * 2 + p) * 128 + c) * 8 + kj;
  out[oh] = (short)hb;
  out[ol] = (short)lb;
}

// -------- x fp32 -> bf16 hi/lo --------
__global__ __launch_bounds__(256) void k_split(const float* __restrict__ x,
                                               short* __restrict__ xhi,
                                               short* __restrict__ xlo) {
  int i = blockIdx.x * 256 + threadIdx.x;
  if (i >= NN * FIN / 4) return;
  float4 v = ((const float4*)x)[i];
  s4 h, l;
  float f, hf;
  f = v.x; h.x = (short)bf_rne(f); hf = __uint_as_float(((unsigned)(unsigned short)h.x) << 16); l.x = (short)bf_rne(f - hf);
  f = v.y; h.y = (short)bf_rne(f); hf = __uint_as_float(((unsigned)(unsigned short)h.y) << 16); l.y = (short)bf_rne(f - hf);
  f = v.z; h.z = (short)bf_rne(f); hf = __uint_as_float(((unsigned)(unsigned short)h.z) << 16); l.z = (short)bf_rne(f - hf);
  f = v.w; h.w = (short)bf_rne(f); hf = __uint_as_float(((unsigned)(unsigned short)h.w) << 16); l.w = (short)bf_rne(f - hf);
  ((s4*)xhi)[i] = h;
  ((s4*)xlo)[i] = l;
}

// ---------------- CSR build (4-way unrolled atomics) ----------------
__global__ void k_hist3(const int* __restrict__ e0, const int* __restrict__ e1,
                        const int* __restrict__ e2, int* __restrict__ deg3) {
  int t = blockIdx.x * blockDim.x + threadIdx.x;
  int st = gridDim.x * blockDim.x;
  for (int base = t * 4; base < 3 * NE; base += st * 4) {
#pragma unroll
    for (int u = 0; u < 4; ++u) {
      int i = base + u;
      if (i < 3 * NE) {
        int rel = i / NE;
        int j = i - rel * NE;
        const int* e = (rel == 0) ? e0 : ((rel == 1) ? e1 : e2);
        atomicAdd(&deg3[rel * NN + e[NE + j]], 1);
      }
    }
  }
}

__global__ __launch_bounds__(1024) void k_bsum(const int* __restrict__ deg3,
                                               int* __restrict__ bsum) {
  __shared__ int s[1024];
  int t = threadIdx.x;
  int i = blockIdx.x * 1024 + t;
  s[t] = (i < NT3) ? deg3[i] : 0;
  __syncthreads();
  for (int off = 512; off > 0; off >>= 1) {
    if (t < off) s[t] += s[t + off];
    __syncthreads();
  }
  if (t == 0) bsum[blockIdx.x] = s[0];
}

__global__ __launch_bounds__(256) void k_scan2(const int* __restrict__ bsum,
                                               int* __restrict__ boffs, int nb) {
  __shared__ int s[256];
  int t = threadIdx.x;
  int v = (t < nb) ? bsum[t] : 0;
  s[t] = v;
  __syncthreads();
  for (int off = 1; off < 256; off <<= 1) {
    int x = (t >= off) ? s[t - off] : 0;
    __syncthreads();
    s[t] += x;
    __syncthreads();
  }
  if (t < nb) boffs[t] = s[t] - v;  // exclusive
}

__global__ __launch_bounds__(1024) void k_rowptr(const int* __restrict__ deg3,
                                                 const int* __restrict__ boffs,
                                                 int* __restrict__ rpA,
                                                 int* __restrict__ cursor3) {
  __shared__ int s[1024];
  int t = threadIdx.x;
  int i = blockIdx.x * 1024 + t;
  int d = (i < NT3) ? deg3[i] : 0;
  s[t] = d;
  __syncthreads();
  for (int off = 1; off < 1024; off <<= 1) {
    int x = (t >= off) ? s[t - off] : 0;
    __syncthreads();
    s[t] += x;
    __syncthreads();
  }
  if (i < NT3) {
    int excl = boffs[blockIdx.x] + s[t] - d;
    int r = (i < NN) ? 0 : ((i < 2 * NN) ? 1 : 2);
    int n = i - r * NN;
    int val = excl - r * NE;
    rpA[r * (NN + 1) + n] = val;
    cursor3[i] = val;
  }
  if (blockIdx.x == 0 && t < 3) rpA[t * (NN + 1) + NN] = NE;
}

// one relation per launch; 4 independent atomic+store chains per thread
__global__ void k_scatter(const int* __restrict__ srcv, const int* __restrict__ dstv,
                          int* __restrict__ cursor, int* __restrict__ csr_src, int n) {
  int t = blockIdx.x * blockDim.x + threadIdx.x;
  int st = gridDim.x * blockDim.x;
  for (int base = t * 4; base < n; base += st * 4) {
    int i0 = base, i1 = base + 1, i2 = base + 2, i3 = base + 3;
    bool v1 = i1 < n, v2 = i2 < n, v3 = i3 < n;
    int d0 = dstv[i0];
    int d1 = v1 ? dstv[i1] : 0;
    int d2 = v2 ? dstv[i2] : 0;
    int d3 = v3 ? dstv[i3] : 0;
    int s0 = srcv[i0];
    int s1 = v1 ? srcv[i1] : 0;
    int s2 = v2 ? srcv[i2] : 0;
    int s3 = v3 ? srcv[i3] : 0;
    int p0 = atomicAdd(&cursor[d0], 1);
    int p1 = v1 ? atomicAdd(&cursor[d1], 1) : 0;
    int p2 = v2 ? atomicAdd(&cursor[d2], 1) : 0;
    int p3 = v3 ? atomicAdd(&cursor[d3], 1) : 0;
    csr_src[p0] = s0;
    if (v1) csr_src[p1] = s1;
    if (v2) csr_src[p2] = s2;
    if (v3) csr_src[p3] = s3;
  }
}

// -------- split-bf16 MFMA GEMM (32x32x16), LDS-staged B, h-store-only epilogue ----
template<int KK>
__global__ __launch_bounds__(256) void k_mgemm(const short* __restrict__ Ahi,
                                               const short* __restrict__ Alo,
                                               const short* __restrict__ BcAll,
                                               __half* __restrict__ houtAll, int M) {
  __shared__ short Bs[2][8192];  // 2 x 16 KB
  const int rel = blockIdx.y;
  const short* Brel = BcAll + (size_t)rel * 4 * KK * 128;
  __half* hout = houtAll + (size_t)rel * NN * HCC;

  const int tid = threadIdx.x;
  const int lane = tid & 63;
  const int w = tid >> 6;
  const int l31 = lane & 31;
  const int lg = lane >> 5;
  const int wrow = blockIdx.x * 64 + (w & 1) * 32;
  const int ch = w >> 1;

  f32x16 acc[4];
#pragma unroll
  for (int t = 0; t < 4; ++t) acc[t] = (f32x16)(0.f);

  const int r = wrow + l31;
  const bool aok = r < M;
  const short* ahp = Ahi + (size_t)r * KK;
  const short* alp = Alo + (size_t)r * KK;
  const int qh = (ch * 2 + 0) * 2 + lg;
  const int ql = (ch * 2 + 1) * 2 + lg;

  const int NK = KK / 16;

#define STAGE(kst, buf)                                                      \
  {                                                                          \
    _Pragma("unroll")                                                        \
    for (int it = 0; it < 4; ++it) {                                         \
      int so = it * 2048 + w * 512;                                          \
      __builtin_amdgcn_global_load_lds(                                      \
          (gas_t)(const void*)(Brel + (size_t)(kst) * 8192 + so + lane * 8), \
          (las_t)(void*)&Bs[buf][so], 16, 0, 0);                             \
    }                                                                        \
  }

#define LOADA(kst, AH, AL)                 \
  {                                        \
    const int k0 = (kst) * 16 + lg * 8;    \
    AH = (sh8){0, 0, 0, 0, 0, 0, 0, 0};    \
    AL = AH;                               \
    if (aok) {                             \
      AH = *(const sh8*)(ahp + k0);        \
      AL = *(const sh8*)(alp + k0);        \
    }                                      \
  }

#define MMBLK(buf, AH, AL)                                                            \
  {                                                                                   \
    _Pragma("unroll")                                                                 \
    for (int t = 0; t < 4; ++t) {                                                     \
      sh8 bhf = *(const sh8*)&Bs[buf][(size_t)(qh * 128 + t * 32 + l31) * 8];         \
      sh8 blf = *(const sh8*)&Bs[buf][(size_t)(ql * 128 + t * 32 + l31) * 8];         \
      acc[t] = __builtin_amdgcn_mfma_f32_32x32x16_bf16(AH, bhf, acc[t], 0, 0, 0);     \
      acc[t] = __builtin_amdgcn_mfma_f32_32x32x16_bf16(AL, bhf, acc[t], 0, 0, 0);     \
      acc[t] = __builtin_amdgcn_mfma_f32_32x32x16_bf16(AH, blf, acc[t], 0, 0, 0);     \
    }                                                                                 \
  }

  sh8 a0h, a0l, a1h, a1l;
  LOADA(0, a0h, a0l);
  STAGE(0, 0);
#pragma unroll
  for (int kst = 0; kst < NK; ++kst) {
    __syncthreads();
    if (kst + 1 < NK) {
      STAGE(kst + 1, (kst & 1) ^ 1);
      if ((kst & 1) == 0) { LOADA(kst + 1, a1h, a1l); }
      else                { LOADA(kst + 1, a0h, a0l); }
    }
    if ((kst & 1) == 0) { MMBLK(0, a0h, a0l); }
    else                { MMBLK(1, a1h, a1l); }
  }
#undef STAGE
#undef LOADA
#undef MMBLK

  // epilogue: h (fp16) store only
#pragma unroll
  for (int v = 0; v < 16; ++v) {
    const int rl = (v & 3) + 8 * (v >> 2) + 4 * lg;
    const int row = wrow + rl;
    if (row < M) {
      __half* hp = hout + (size_t)row * 256 + ch * 128 + l31;
#pragma unroll
      for (int t = 0; t < 4; ++t) hp[t * 32] = __float2half(acc[t][v]);
    }
  }
}

// -------- alpha: one wave per (rel,node); coalesced 512B row read --------
__global__ __launch_bounds__(256) void k_alpha3(const __half* __restrict__ h3,
                                                const float* __restrict__ asAll,
                                                const float* __restrict__ adAll,
                                                float* __restrict__ als3,
                                                float* __restrict__ ald3) {
  int wid = (blockIdx.x * 256 + threadIdx.x) >> 6;
  int lane = threadIdx.x & 63;
  if (wid >= NT3) return;
  int rel = wid / NN;
  int n = wid - rel * NN;
  h4 hv4 = *(const h4*)&h3[((size_t)rel * NN + n) * HCC + lane * 4];
  float hx = __half2float(hv4.x), hy = __half2float(hv4.y);
  float hz = __half2float(hv4.z), hw = __half2float(hv4.w);
  float4 s4v = *(const float4*)&asAll[rel * HCC + lane * 4];
  float4 d4v = *(const float4*)&adAll[rel * HCC + lane * 4];
  float ss = hx * s4v.x + hy * s4v.y + hz * s4v.z + hw * s4v.w;
  float sd = hx * d4v.x + hy * d4v.y + hz * d4v.z + hw * d4v.w;
#pragma unroll
  for (int m = 1; m < 16; m <<= 1) {
    ss += __shfl_xor(ss, m);
    sd += __shfl_xor(sd, m);
  }
  if ((lane & 15) == 0) {
    int head = lane >> 4;
    als3[((size_t)rel * NN + n) * 4 + head] = ss;
    ald3[((size_t)rel * NN + n) * 4 + head] = sd;
  }
}

// ---------------- fused 3-relation gather core (inline weights, 4-deep) ----------------
template<bool SL>
__device__ __forceinline__ void gat_rel(int n, int head, size_t loff,
                                        const __half* __restrict__ h,
                                        const float* __restrict__ als,
                                        const float* __restrict__ ald,
                                        const int* __restrict__ rp,
                                        const int* __restrict__ cs,
                                        float& ox, float& oy, float& oz, float& ow) {
  float ad = ald[n * 4 + head];
  int rs = rp[n], re = rp[n + 1];
  float ax = 0.f, ay = 0.f, az = 0.f, aw = 0.f, wsum = 0.f;
  int i = rs;
  for (; i + 4 <= re; i += 4) {
    int s0 = cs[i], s1 = cs[i + 1], s2 = cs[i + 2], s3 = cs[i + 3];
    float al0 = als[s0 * 4 + head];
    float al1 = als[s1 * 4 + head];
    float al2 = als[s2 * 4 + head];
    float al3 = als[s3 * 4 + head];
    h4 v0 = *(const h4*)&h[(size_t)s0 * HCC + loff];
    h4 v1 = *(const h4*)&h[(size_t)s1 * HCC + loff];
    h4 v2 = *(const h4*)&h[(size_t)s2 * HCC + loff];
    h4 v3 = *(const h4*)&h[(size_t)s3 * HCC + loff];
    float w0 = edge_w(al0 + ad), w1 = edge_w(al1 + ad);
    float w2 = edge_w(al2 + ad), w3 = edge_w(al3 + ad);
    wsum += (w0 + w1) + (w2 + w3);
    ax = fmaf(w0, __half2float(v0.x), ax); ay = fmaf(w0, __half2float(v0.y), ay);
    az = fmaf(w0, __half2float(v0.z), az); aw = fmaf(w0, __half2float(v0.w), aw);
    ax = fmaf(w1, __half2float(v1.x), ax); ay = fmaf(w1, __half2float(v1.y), ay);
    az = fmaf(w1, __half2float(v1.z), az); aw = fmaf(w1, __half2float(v1.w), aw);
    ax = fmaf(w2, __half2float(v2.x), ax); ay = fmaf(w2, __half2float(v2.y), ay);
    az = fmaf(w2, __half2float(v2.z), az); aw = fmaf(w2, __half2float(v2.w), aw);
    ax = fmaf(w3, __half2float(v3.x), ax); ay = fmaf(w3, __half2float(v3.y), ay);
    az = fmaf(w3, __half2float(v3.z), az); aw = fmaf(w3, __half2float(v3.w), aw);
  }
  for (; i < re; ++i) {
    int s = cs[i];
    float w = edge_w(als[s * 4 + head] + ad);
    wsum += w;
    h4 hv = *(const h4*)&h[(size_t)s * HCC + loff];
    ax = fmaf(w, __half2float(hv.x), ax);
    ay = fmaf(w, __half2float(hv.y), ay);
    az = fmaf(w, __half2float(hv.z), az);
    aw = fmaf(w, __half2float(hv.w), aw);
  }
  if (SL) {
    float w = edge_w(als[n * 4 + head] + ad);
    wsum += w;
    h4 hv = *(const h4*)&h[(size_t)n * HCC + loff];
    ax = fmaf(w, __half2float(hv.x), ax);
    ay = fmaf(w, __half2float(hv.y), ay);
    az = fmaf(w, __half2float(hv.z), az);
    aw = fmaf(w, __half2float(hv.w), aw);
  }
  float inv = 1.0f / (wsum + 1e-16f);
  ox = fmaf(ax, inv, ox);
  oy = fmaf(ay, inv, oy);
  oz = fmaf(az, inv, oz);
  ow = fmaf(aw, inv, ow);
}

// concat layer-1 gather: o1hi/o1lo[n,256] = split-bf16 relu(sum_r gat + sum_r bias)
__global__ __launch_bounds__(256) void k_gather3c(const __half* __restrict__ h3,
                                                  const float* __restrict__ als3,
                                                  const float* __restrict__ ald3,
                                                  const int* __restrict__ rpA,
                                                  const int* __restrict__ csAll,
                                                  const float* __restrict__ bias,
                                                  short* __restrict__ o1hi,
                                                  short* __restrict__ o1lo) {
  int gid = blockIdx.x * blockDim.x + threadIdx.x;
  int n = gid >> 6;
  int lane = threadIdx.x & 63;
  if (n >= NN) return;
  int head = lane >> 4;
  size_t loff = (size_t)lane * 4;
  const size_t HS = (size_t)NN * HCC;
  const size_t AS = (size_t)NN * 4;
  float ox = 0.f, oy = 0.f, oz = 0.f, ow = 0.f;
  gat_rel<false>(n, head, loff, h3,          als3,          ald3,          rpA,                csAll,          ox, oy, oz, ow);
  gat_rel<true >(n, head, loff, h3 + HS,     als3 + AS,     ald3 + AS,     rpA + (NN + 1),     csAll + NE,     ox, oy, oz, ow);
  gat_rel<true >(n, head, loff, h3 + 2 * HS, als3 + 2 * AS, ald3 + 2 * AS, rpA + 2 * (NN + 1), csAll + 2 * NE, ox, oy, oz, ow);
  float4 b0 = *(const float4*)&bias[lane * 4];
  float4 b1 = *(const float4*)&bias[HCC + lane * 4];
  float4 b2 = *(const float4*)&bias[2 * HCC + lane * 4];
  float vv[4];
  vv[0] = fmaxf(ox + b0.x + b1.x + b2.x, 0.f);
  vv[1] = fmaxf(oy + b0.y + b1.y + b2.y, 0.f);
  vv[2] = fmaxf(oz + b0.z + b1.z + b2.z, 0.f);
  vv[3] = fmaxf(ow + b0.w + b1.w + b2.w, 0.f);
  s4 hv, lv;
  short* hp = (short*)&hv;
  short* lp = (short*)&lv;
#pragma unroll
  for (int j = 0; j < 4; ++j) {
    unsigned short hb = bf_rne(vv[j]);
    float hf = __uint_as_float(((unsigned)hb) << 16);
    hp[j] = (short)hb;
    lp[j] = (short)bf_rne(vv[j] - hf);
  }
  *(s4*)&o1hi[(size_t)n * HCC + loff] = hv;
  *(s4*)&o1lo[(size_t)n * HCC + loff] = lv;
}

// layer-2 gather + fused final: outp[n,64] = relu(mean + biases) @ Wl + bl
__global__ __launch_bounds__(256) void k_gather3f(const __half* __restrict__ h3,
                                                  const float* __restrict__ als3,
                                                  const float* __restrict__ ald3,
                                                  const int* __restrict__ rpA,
                                                  const int* __restrict__ csAll,
                                                  const float* __restrict__ bias,
                                                  const float* __restrict__ Wl,
                                                  const float* __restrict__ bl,
                                                  float* __restrict__ outp) {
  __shared__ float Ws[64 * 64];
  for (int i = threadIdx.x; i < 4096; i += 256) Ws[i] = Wl[i];
  __syncthreads();  // safe: grid covers exactly NN*64 threads
  int gid = blockIdx.x * blockDim.x + threadIdx.x;
  int n = gid >> 6;
  int lane = threadIdx.x & 63;
  if (n >= NN) return;
  int head = lane >> 4;
  size_t loff = (size_t)lane * 4;
  const size_t HS = (size_t)NN * HCC;
  const size_t AS = (size_t)NN * 4;
  float ox = 0.f, oy = 0.f, oz = 0.f, ow = 0.f;
  gat_rel<false>(n, head, loff, h3,          als3,          ald3,          rpA,                csAll,          ox, oy, oz, ow);
  gat_rel<true >(n, head, loff, h3 + HS,     als3 + AS,     ald3 + AS,     rpA + (NN + 1),     csAll + NE,     ox, oy, oz, ow);
  gat_rel<true >(n, head, loff, h3 + 2 * HS, als3 + 2 * AS, ald3 + 2 * AS, rpA + 2 * (NN + 1), csAll + 2 * NE, ox, oy, oz, ow);
  ox += __shfl_xor(ox, 16); oy += __shfl_xor(oy, 16);
  oz += __shfl_xor(oz, 16); ow += __shfl_xor(ow, 16);
  ox += __shfl_xor(ox, 32); oy += __shfl_xor(oy, 32);
  oz += __shfl_xor(oz, 32); ow += __shfl_xor(ow, 32);
  int q0 = lane & 15;
  float4 b0 = *(const float4*)&bias[q0 * 4];
  float4 b1 = *(const float4*)&bias[OC + q0 * 4];
  float4 b2 = *(const float4*)&bias[2 * OC + q0 * 4];
  float x0 = fmaxf(0.25f * ox + b0.x + b1.x + b2.x, 0.f);
  float x1 = fmaxf(0.25f * oy + b0.y + b1.y + b2.y, 0.f);
  float x2 = fmaxf(0.25f * oz + b0.z + b1.z + b2.z, 0.f);
  float x3 = fmaxf(0.25f * ow + b0.w + b1.w + b2.w, 0.f);
  float acc = bl[lane];
#pragma unroll
  for (int q = 0; q < 16; ++q) {
    float xa = __shfl(x0, q);
    float xb = __shfl(x1, q);
    float xc = __shfl(x2, q);
    float xd = __shfl(x3, q);
    acc = fmaf(xa, Ws[(4 * q + 0) * 64 + lane], acc);
    acc = fmaf(xb, Ws[(4 * q + 1) * 64 + lane], acc);
    acc = fmaf(xc, Ws[(4 * q + 2) * 64 + lane], acc);
    acc = fmaf(xd, Ws[(4 * q + 3) * 64 + lane], acc);
  }
  outp[(size_t)n * OC + lane] = acc;
}

extern "C" void kernel_launch(void* const* d_in, const int* in_sizes, int n_in,
                              void* d_out, int out_size, void* d_ws, size_t ws_size,
                              hipStream_t stream) {
  const float* x   = (const float*)d_in[0];
  const int* e_b   = (const int*)d_in[1];
  const int* e_sp  = (const int*)d_in[2];
  const int* e_si  = (const int*)d_in[3];
  const float* W1  = (const float*)d_in[4];
  const float* a1s = (const float*)d_in[5];
  const float* a1d = (const float*)d_in[6];
  const float* b1  = (const float*)d_in[7];
  const float* W2  = (const float*)d_in[8];
  const float* a2s = (const float*)d_in[9];
  const float* a2d = (const float*)d_in[10];
  const float* b2  = (const float*)d_in[11];
  const float* Wl  = (const float*)d_in[12];
  const float* bl  = (const float*)d_in[13];
  float* out = (float*)d_out;

  char* ws = (char*)d_ws;
  size_t off = 0;
  auto alloc = [&](size_t b) {
    char* p = ws + off;
    off += (b + 255) & ~(size_t)255;
    return p;
  };
  __half* h3  = (__half*)alloc((size_t)3 * NN * HCC * 2);   // 76.8 MB
  short* o1hi = (short*)alloc((size_t)NN * HCC * 2);        // 25.6 MB
  short* o1lo = (short*)alloc((size_t)NN * HCC * 2);        // 25.6 MB
  short* xhi  = (short*)alloc((size_t)NN * FIN * 2);        // 12.8 MB
  short* xlo  = (short*)alloc((size_t)NN * FIN * 2);        // 12.8 MB
  float* als3 = (float*)alloc((size_t)3 * NN * 4 * 4);
  float* ald3 = (float*)alloc((size_t)3 * NN * 4 * 4);
  int* deg3    = (int*)alloc((size_t)NT3 * 4);
  int* cursor3 = (int*)alloc((size_t)NT3 * 4);
  int* rpA     = (int*)alloc((size_t)3 * (NN + 1) * 4);
  int* bsum    = (int*)alloc(256 * 4);
  int* boffs   = (int*)alloc(256 * 4);
  short* Wc1   = (short*)alloc((size_t)3 * 4 * FIN * 128 * 2);
  short* Wc2   = (short*)alloc((size_t)3 * 4 * HCC * 128 * 2);
  int* csAll   = (int*)alloc((size_t)3 * NE * 4);

  const int* edges[3] = {e_b, e_sp, e_si};

  // weight pre-split + x pre-split (tiny)
  k_prep<FIN><<<(3 * FIN * 256 + 255) / 256, 256, 0, stream>>>(W1, Wc1);
  k_prep<HCC><<<(3 * HCC * 256 + 255) / 256, 256, 0, stream>>>(W2, Wc2);
  k_split<<<(NN * FIN / 4 + 255) / 256, 256, 0, stream>>>(x, xhi, xlo);

  // CSR build
  hipMemsetAsync(deg3, 0, (size_t)NT3 * 4, stream);
  k_hist3<<<2048, 256, 0, stream>>>(e_b, e_sp, e_si, deg3);
  const int NB = (NT3 + 1023) / 1024;  // 147
  k_bsum<<<NB, 1024, 0, stream>>>(deg3, bsum);
  k_scan2<<<1, 256, 0, stream>>>(bsum, boffs, NB);
  k_rowptr<<<NB, 1024, 0, stream>>>(deg3, boffs, rpA, cursor3);
  for (int r = 0; r < 3; ++r)
    k_scatter<<<2048, 256, 0, stream>>>(edges[r], edges[r] + NE, cursor3 + r * NN,
                                        csAll + (size_t)r * NE, NE);

  const int gblocks = (NN + 63) / 64;   // 782
  const int ablocks = (NN * 64) / 256;  // 12500
  const int wblocks = (NT3 + 3) / 4;    // one wave per (rel,node)

  // layer 1
  k_mgemm<FIN><<<dim3(gblocks, 3), 256, 0, stream>>>(xhi, xlo, Wc1, h3, NN);
  k_alpha3<<<wblocks, 256, 0, stream>>>(h3, a1s, a1d, als3, ald3);
  k_gather3c<<<ablocks, 256, 0, stream>>>(
      h3, als3, ald3, rpA, csAll, b1, o1hi, o1lo);

  // layer 2 (+ fused final linear)
  k_mgemm<HCC><<<dim3(gblocks, 3), 256, 0, stream>>>(o1hi, o1lo, Wc2, h3, NN);
  k_alpha3<<<wblocks, 256, 0, stream>>>(h3, a2s, a2d, als3, ald3);
  k_gather3f<<<ablocks, 256, 0, stream>>>(
      h3, als3, ald3, rpA, csAll, b2, Wl, bl, out);
}